// Round 7
// baseline (2128.828 us; speedup 1.0000x reference)
//
#include <hip/hip_runtime.h>

typedef __attribute__((ext_vector_type(8))) short s8v;   // 8 x bf16 (4 VGPRs)
typedef __attribute__((ext_vector_type(4))) float f4v;   // MFMA accumulator

#define BB 8
#define TT 500
#define UU 120
#define UP1 121
#define VV 128
#define HH 320
#define G4 1280

// ---------------- helpers ----------------
__device__ __forceinline__ unsigned short f2bf(float x) {
  unsigned u = __builtin_bit_cast(unsigned, x);
  unsigned r = (u + 0x7FFFu + ((u >> 16) & 1u)) >> 16;  // RNE
  return (unsigned short)r;
}
__device__ __forceinline__ float sigf(float x)   { return 1.f / (1.f + __expf(-x)); }
__device__ __forceinline__ float tanh_f(float x) { return 2.f / (1.f + __expf(-2.f * x)) - 1.f; }

// agent-scope (L3-coherent) relaxed atomics — proven transport
__device__ __forceinline__ unsigned ald32(const unsigned* p) {
  return __hip_atomic_load((unsigned*)p, __ATOMIC_RELAXED, __HIP_MEMORY_SCOPE_AGENT);
}
__device__ __forceinline__ void ast32(unsigned* p, unsigned v) {
  __hip_atomic_store(p, v, __ATOMIC_RELAXED, __HIP_MEMORY_SCOPE_AGENT);
}

// ---------------- prep: zero step-counters + out ----------------
__global__ void prep_zero(unsigned* cn0, unsigned* cn1, unsigned* cnd, float* out) {
  int i = threadIdx.x;
  cn0[i] = 0u; cn1[i] = 0u; cnd[i] = 0u;
  if (i == 0) out[0] = 0.f;
}

// ---------------- prep: bf16 conversions + bias folds ----------------
__global__ void prep_w(
    const float* __restrict__ whh0, const float* __restrict__ wih1,
    const float* __restrict__ whh1, const float* __restrict__ whhd,
    const float* __restrict__ wih0, const float* __restrict__ xs,
    const float* __restrict__ ewo,  const float* __restrict__ dwo,
    const float* __restrict__ bih1, const float* __restrict__ bhh1,
    const float* __restrict__ bih0, const float* __restrict__ bhh0,
    ushort* __restrict__ wb, ushort* __restrict__ wih0b, ushort* __restrict__ xsb,
    ushort* __restrict__ wob, ushort* __restrict__ dwob,
    float* __restrict__ bias1p, float* __restrict__ b0s)
{
  int i = blockIdx.x * blockDim.x + threadIdx.x;
  if (i < 1638400) {                       // 4 recurrent-ish mats [1280][320]
    int m = i / 409600, e = i - m * 409600;
    const float* src = (m == 0) ? whh0 : (m == 1) ? wih1 : (m == 2) ? whh1 : whhd;
    wb[i] = f2bf(src[e]);
  } else if (i < 1761280) {                // Wih0 [1280][80] -> [1280][96] zero-padded
    int e = i - 1638400;
    int row = e / 96, k = e - row * 96;
    wih0b[e] = (k < 80) ? f2bf(wih0[row * 80 + k]) : (ushort)0;
  } else if (i < 2145280) {                // xs [4000][80] -> [4000][96] zero-padded
    int e = i - 1761280;
    int row = e / 96, k = e - row * 96;
    xsb[e] = (k < 80) ? f2bf(xs[row * 80 + k]) : (ushort)0;
  } else if (i < 2186240) {                // enc_Wo [128][320]
    int e = i - 2145280;
    wob[e] = f2bf(ewo[e]);
  } else if (i < 2227200) {                // dec_Wo [128][320]
    int e = i - 2186240;
    dwob[e] = f2bf(dwo[e]);
  } else if (i < 2228480) {                // bias1 permuted [unit][gate]
    int e = i - 2227200;
    int uq = e >> 2, gq = e & 3;
    bias1p[e] = bih1[gq * HH + uq] + bhh1[gq * HH + uq];
  } else if (i < 2229760) {                // bih0+bhh0 summed (gate-row order)
    int e = i - 2228480;
    b0s[e] = bih0[e] + bhh0[e];
  }
}

// ---------------- xproj for layer0: [4000,96]bf16 @ [96,1280] -> xp0[b][t][u][g] f32 ----------------
__global__ __launch_bounds__(256) void xproj0_mfma(
    const ushort* __restrict__ xsb, const ushort* __restrict__ wih0b,
    const float* __restrict__ b0s, float* __restrict__ xp0)
{
  const int mt = blockIdx.x;                 // 250 tiles of 16 (b,t)-rows
  const int wave = threadIdx.x >> 6, lane = threadIdx.x & 63;
  const int q = lane >> 4, n16 = lane & 15;
  s8v a[3];
#pragma unroll
  for (int kt = 0; kt < 3; kt++)
    a[kt] = *(const s8v*)(xsb + (mt * 16 + n16) * 96 + kt * 32 + q * 8);
  for (int nt = wave; nt < 80; nt += 4) {
    s8v bf[3];
#pragma unroll
    for (int kt = 0; kt < 3; kt++)
      bf[kt] = *(const s8v*)(wih0b + (nt * 16 + n16) * 96 + kt * 32 + q * 8);
    f4v acc = {0.f, 0.f, 0.f, 0.f};
#pragma unroll
    for (int kt = 0; kt < 3; kt++)
      acc = __builtin_amdgcn_mfma_f32_16x16x32_bf16(a[kt], bf[kt], acc, 0, 0, 0);
    const int gr = nt * 16 + n16;            // D col = gate row
    const int gg = gr / HH;
    const int uu = gr - gg * HH;
    const float bias = b0s[gr];
#pragma unroll
    for (int r = 0; r < 4; r++) {
      int bt = mt * 16 + 4 * q + r;          // D row = (b,t) row
      xp0[(size_t)bt * G4 + uu * 4 + gg] = acc[r] + bias;
    }
  }
}

// ---------------- decoder input projection: one-hot gather ----------------
__global__ __launch_bounds__(256) void xprojd_g(
    const int* __restrict__ ys, const float* __restrict__ dWih,
    const float* __restrict__ dbih, const float* __restrict__ dbhh,
    float* __restrict__ xpd)
{
  const int blk = blockIdx.x;                // 968 = 8 * 121
  const int b = blk / UP1, u = blk - b * UP1;
  int colv = -1;
  if (u > 0) colv = ys[b * UU + (u - 1)] - 1;   // embed row id>=1 -> one-hot at id-1
  for (int i = threadIdx.x; i < G4; i += 256) {
    int uu = i >> 2, gg = i & 3;
    int row = gg * HH + uu;
    float v = dbih[row] + dbhh[row];
    if (colv >= 0) v += dWih[row * 127 + colv];
    xpd[((size_t)b * UP1 + u) * G4 + i] = v;
  }
}

// ======================================================================
// Fused recurrences v5: R6 transport + forced weight residency + packed h.
// 20 WGs x 512 thr (8 waves): wg0-4 stage0, wg5-9 stage1, wg10-14 dec,
// wg15-19 relay (xp1 = Wih1@h0[s+1] + b1, one-way).
// Fixes from R6 counters:
//  (1) VGPR_Count=76 < 80 showed weights were L2-streamed EVERY step
//      (~164KB/step/WG ~ 2900cy). Now: tile0 (40 VGPR) in regs — small
//      enough that the allocator provably keeps it — and tile1 in an 80KB
//      LDS array written once, read via ds_read_b128 (~120cy/step).
//  (2) WRITE_SIZE=102MB showed 16-line write-amp on h stores. h layout is
//      now [t][unit][batch]: a wave's 16 stores land in 2-4 lines, and the
//      consumer bulk read is 1280 contiguous bytes per wave. LDS relay
//      transposes on write (bank-clean).
// Transport unchanged: counter gate (hierarchical publish), sleepless
// first-64 spins, tagged u32/f32 payloads, deferred C-init resolve.
// ======================================================================
__global__ __launch_bounds__(512, 1) void lstm_fused(
    const ushort* __restrict__ wb, const float* __restrict__ b1p,
    const float* __restrict__ xp0, const float* __restrict__ xpd,
    unsigned* __restrict__ h0u, unsigned* __restrict__ h1u, unsigned* __restrict__ hdu,
    unsigned* __restrict__ xp1u,
    unsigned* __restrict__ cn0, unsigned* __restrict__ cn1, unsigned* __restrict__ cnd)
{
  __shared__ ushort hbS[2][16][328];         // 21KB  h double-buffer [b][u]
  __shared__ s8v wlds[8][10][64];            // 80KB  tile1 weight frags
  __shared__ unsigned ldsCnt;

  const int wg = blockIdx.x;
  const int tid = threadIdx.x;
  const int wave = tid >> 6, lane = tid & 63;
  const int q = lane >> 4, n16 = lane & 15;
  const int uloc = n16 >> 2, g = n16 & 3;
  const int bcol = n16 & 7;
  const bool act = (n16 < BB);

  // zero both LDS h buffers (t=0 state = zeros; rows 8..15 stay zero forever)
  for (int i = tid; i < 2 * 16 * 328; i += 512) ((ushort*)hbS)[i] = 0;
  if (tid == 0) ldsCnt = 0u;

  if (wg >= 15) {
    // ================= relay: xp1[s] = Wih1 @ h0[s+1] + b1 =================
    const int rw = wg - 15;
    const int w = rw * 8 + wave;
    const int ubase = w * 8;
    const ushort* Win = wb + 409600;         // Wih1
    // tile0 -> regs (40 VGPR), tile1 -> LDS
    s8v afr0[10];
    {
      const int arow0 = g * HH + ubase + uloc;
      const int arow1 = g * HH + ubase + 4 + uloc;
#pragma unroll
      for (int kt = 0; kt < 10; kt++) {
        afr0[kt] = *(const s8v*)(Win + arow0 * HH + kt * 32 + q * 8);
        wlds[wave][kt][lane] = *(const s8v*)(Win + arow1 * HH + kt * 32 + q * 8);
      }
    }
    f4v bias4[2];
#pragma unroll
    for (int tile = 0; tile < 2; tile++)
      bias4[tile] = *(const f4v*)(b1p + (ubase + tile * 4 + q) * 4);
    __syncthreads();

    for (int s = 0; s < TT; s++) {
      const int pb = s & 1;
      // gate: stage0 has published h0[s+1]
      {
        int tries = 0;
        while (ald32(cn0 + s + 1) != 5u) {
          if (++tries > 64) __builtin_amdgcn_s_sleep(1);
          if (tries > (1 << 17)) break;
        }
      }
      // bulk tagged read of flat slice [wave*320, wave*320+320) of h0[s+1]
      {
        const unsigned* src = h0u + (size_t)(s + 1) * 2560 + wave * 320;
        unsigned v[5];
        int tries = 0;
        for (;;) {
#pragma unroll
          for (int j = 0; j < 5; j++) v[j] = ald32(src + j * 64 + lane);
          unsigned a = v[0] & v[1] & v[2] & v[3] & v[4];
          if (__all((int)(a & 1u)) || ++tries > (1 << 17)) break;
          if (tries > 64) __builtin_amdgcn_s_sleep(1);
        }
#pragma unroll
        for (int j = 0; j < 5; j++) {
          int f = wave * 320 + j * 64 + lane;          // u = f>>3, b = f&7
          hbS[pb][f & 7][f >> 3] = (ushort)(v[j] >> 16);
        }
      }
      __syncthreads();

      f4v acc[2];
      acc[0] = bias4[0]; acc[1] = bias4[1];
#pragma unroll
      for (int kt = 0; kt < 10; kt++) {
        s8v b = *(const s8v*)&hbS[pb][n16][kt * 32 + q * 8];
        acc[0] = __builtin_amdgcn_mfma_f32_16x16x32_bf16(afr0[kt], b, acc[0], 0, 0, 0);
        s8v a1 = wlds[wave][kt][lane];
        acc[1] = __builtin_amdgcn_mfma_f32_16x16x32_bf16(a1, b, acc[1], 0, 0, 0);
      }
      if (act) {
#pragma unroll
        for (int tile = 0; tile < 2; tile++) {
          unsigned* dp = xp1u + (size_t)((unsigned)s * 8u + (unsigned)n16) * G4
                       + (unsigned)((ubase + tile * 4 + q) * 4);
#pragma unroll
          for (int r = 0; r < 4; r++)
            ast32(dp + r, __float_as_uint(acc[tile][r]) | 1u);   // LSB tag on f32
        }
      }
      // no counter publish: consumers use per-element tags (one-way edge)
    }
    return;
  }

  // ================= recurrent stages =================
  const int stage = wg / 5;
  const int gw = wg - stage * 5;
  const int w = gw * 8 + wave;              // wave-in-stage [0,40)
  const int ubase = w * 8;                  // this wave owns units [ubase, ubase+8)

  const ushort* A = wb + (stage == 0 ? 0 : (stage == 1 ? 819200 : 1228800));
  // tile0 -> regs (40 VGPR), tile1 -> LDS
  s8v afr0[10];
  {
    const int arow0 = g * HH + ubase + uloc;
    const int arow1 = g * HH + ubase + 4 + uloc;
#pragma unroll
    for (int kt = 0; kt < 10; kt++) {
      afr0[kt] = *(const s8v*)(A + arow0 * HH + kt * 32 + q * 8);
      wlds[wave][kt][lane] = *(const s8v*)(A + arow1 * HH + kt * 32 + q * 8);
    }
  }

  const int steps = (stage == 2) ? UP1 : TT;
  unsigned* hio = (stage == 0) ? h0u : ((stage == 1) ? h1u : hdu);
  unsigned* cS  = (stage == 0) ? cn0 : ((stage == 1) ? cn1 : cnd);

  const float* xq = 0;
  if (stage == 0)      xq = xp0 + (size_t)bcol * TT * G4;
  else if (stage == 2) xq = xpd + (size_t)bcol * UP1 * G4;

  float c0 = 0.f, c1 = 0.f;
  __syncthreads();                          // LDS zeros + weight-LDS visible

  for (int t = 0; t < steps; t++) {
    const int pb = t & 1;

    // ---- pre-issue C-init inputs; consumed after the MFMA block ----
    f4v xq4[2];
    unsigned xv[2][4];
    if (stage != 1) {
#pragma unroll
      for (int tile = 0; tile < 2; tile++)
        xq4[tile] = *(const f4v*)(xq + (size_t)t * G4 + (ubase + tile * 4 + q) * 4);
    } else {
#pragma unroll
      for (int tile = 0; tile < 2; tile++) {
        const unsigned* xpp = xp1u + (size_t)((unsigned)t * 8u + (unsigned)bcol) * G4
                            + (unsigned)((ubase + tile * 4 + q) * 4);
#pragma unroll
        for (int r = 0; r < 4; r++) xv[tile][r] = ald32(xpp + r);
      }
    }

    // ---- gate: all 5 WGs of this stage published h[t] ----
    if (t > 0) {
      int tries = 0;
      while (ald32(cS + t) != 5u) {
        if (++tries > 64) __builtin_amdgcn_s_sleep(1);
        if (tries > (1 << 17)) break;
      }
    }

    // ---- bulk tagged read of flat slice, transpose-relay into LDS ----
    if (t > 0) {
      const unsigned* src = hio + (size_t)t * 2560 + wave * 320;
      unsigned v[5];
      int tries = 0;
      for (;;) {
#pragma unroll
        for (int j = 0; j < 5; j++) v[j] = ald32(src + j * 64 + lane);
        unsigned a = v[0] & v[1] & v[2] & v[3] & v[4];
        if (__all((int)(a & 1u)) || ++tries > (1 << 17)) break;
        if (tries > 64) __builtin_amdgcn_s_sleep(1);
      }
#pragma unroll
      for (int j = 0; j < 5; j++) {
        int f = wave * 320 + j * 64 + lane;            // u = f>>3, b = f&7
        hbS[pb][f & 7][f >> 3] = (ushort)(v[j] >> 16);
      }
    }
    __syncthreads();

    // ---- MFMAs: B-frags from LDS h(t); tile1 A-frags from LDS ----
    f4v acc[2];
    acc[0] = (f4v){0.f, 0.f, 0.f, 0.f};
    acc[1] = (f4v){0.f, 0.f, 0.f, 0.f};
#pragma unroll
    for (int kt = 0; kt < 10; kt++) {
      s8v b = *(const s8v*)&hbS[pb][n16][kt * 32 + q * 8];
      acc[0] = __builtin_amdgcn_mfma_f32_16x16x32_bf16(afr0[kt], b, acc[0], 0, 0, 0);
      s8v a1 = wlds[wave][kt][lane];
      acc[1] = __builtin_amdgcn_mfma_f32_16x16x32_bf16(a1, b, acc[1], 0, 0, 0);
    }

    // ---- resolve C-init (deferred add; stage1 tag-spins on relay output) ----
    if (stage != 1) {
#pragma unroll
      for (int tile = 0; tile < 2; tile++) {
        acc[tile][0] += xq4[tile][0]; acc[tile][1] += xq4[tile][1];
        acc[tile][2] += xq4[tile][2]; acc[tile][3] += xq4[tile][3];
      }
    } else {
      int tries = 0;
      for (;;) {
        unsigned m = xv[0][0] & xv[0][1] & xv[0][2] & xv[0][3]
                   & xv[1][0] & xv[1][1] & xv[1][2] & xv[1][3];
        bool ok = (!act) || ((m & 1u) != 0u);
        if (__all((int)ok) || ++tries > (1 << 17)) break;
        if (tries > 64) __builtin_amdgcn_s_sleep(1);
#pragma unroll
        for (int tile = 0; tile < 2; tile++) {
          const unsigned* xpp = xp1u + (size_t)((unsigned)t * 8u + (unsigned)bcol) * G4
                              + (unsigned)((ubase + tile * 4 + q) * 4);
#pragma unroll
          for (int r = 0; r < 4; r++) xv[tile][r] = ald32(xpp + r);
        }
      }
#pragma unroll
      for (int tile = 0; tile < 2; tile++)
#pragma unroll
        for (int r = 0; r < 4; r++)
          acc[tile][r] += __uint_as_float(xv[tile][r] & ~1u);
    }

    // ---- lane-local LSTM cell ----
    float hv0, hv1;
    {
      float ig = sigf(acc[0][0]), fg = sigf(acc[0][1]);
      float gv = tanh_f(acc[0][2]), og = sigf(acc[0][3]);
      c0 = fg * c0 + ig * gv; hv0 = og * tanh_f(c0);
    }
    {
      float ig = sigf(acc[1][0]), fg = sigf(acc[1][1]);
      float gv = tanh_f(acc[1][2]), og = sigf(acc[1][3]);
      c1 = fg * c1 + ig * gv; hv1 = og * tanh_f(c1);
    }
    if (act) {
      // packed [u][b] store: wave's 16 stores span 2-4 cache lines
      unsigned* dst = hio + (size_t)(t + 1) * 2560;
      ast32(dst + (ubase + q) * 8 + n16,     (((unsigned)f2bf(hv0)) << 16) | 1u);
      ast32(dst + (ubase + 4 + q) * 8 + n16, (((unsigned)f2bf(hv1)) << 16) | 1u);
    }

    // ---- hierarchical publish: wave drains, 8th wave of WG bumps stage counter ----
    asm volatile("s_waitcnt vmcnt(0)" ::: "memory");
    if (lane == 0) {
      unsigned old = atomicAdd(&ldsCnt, 1u);
      if (old == 8u * (unsigned)(t + 1) - 1u) atomicAdd(cS + t + 1, 1u);
    }
  }
}

// ---------------- output projections: h(tagged u32, [u][b]) @ Wo^T -> out2[t][16][128] ----------------
__global__ __launch_bounds__(256) void proj_mfma(
    const unsigned* __restrict__ hseq, const ushort* __restrict__ wo,
    const float* __restrict__ bo, float* __restrict__ out2)
{
  __shared__ ushort hl[16][328];
  const int t = blockIdx.x;
  const int tid = threadIdx.x;
  const int wave = tid >> 6, lane = tid & 63;
  const int q = lane >> 4, n16 = lane & 15;
  // zero rows 8..15 (unused MFMA B-columns)
  for (int i = tid; i < 8 * 328; i += 256) hl[8 + i / 328][i % 328] = 0;
  // coalesced load + transpose: flat idx f -> u=f>>3, b=f&7
  for (int f = tid; f < 2560; f += 256) {
    unsigned v = hseq[(size_t)(t + 1) * 2560 + f];
    hl[f & 7][f >> 3] = (ushort)(v >> 16);
  }
  __syncthreads();
  s8v a[10];
#pragma unroll
  for (int kt = 0; kt < 10; kt++)
    a[kt] = *(const s8v*)&hl[n16][kt * 32 + q * 8];
  for (int j = 0; j < 2; j++) {
    int nt = wave * 2 + j;
    s8v bf[10];
#pragma unroll
    for (int kt = 0; kt < 10; kt++)
      bf[kt] = *(const s8v*)(wo + (nt * 16 + n16) * HH + kt * 32 + q * 8);
    f4v acc = {0.f, 0.f, 0.f, 0.f};
#pragma unroll
    for (int kt = 0; kt < 10; kt++)
      acc = __builtin_amdgcn_mfma_f32_16x16x32_bf16(a[kt], bf[kt], acc, 0, 0, 0);
    int v = nt * 16 + n16;
    float bias = bo[v];
    if (q < 2) {
#pragma unroll
      for (int r = 0; r < 4; r++) {
        int b = 4 * q + r;                   // D row = batch
        out2[((size_t)t * 16 + b) * VV + v] = acc[r] + bias;
      }
    }
  }
}

// ---------------- per-cell logsumexp over V: produce lb[b][t][u], ly[b][t][u] ----------------
__global__ __launch_bounds__(256) void lse_kernel(
    const float* __restrict__ enc2, const float* __restrict__ dec2,
    const int* __restrict__ ys, float* __restrict__ lb, float* __restrict__ ly)
{
  const int blk = blockIdx.x;                // 4000 = 8*500
  const int b = blk / TT, t = blk - b * TT;
  const int wave = threadIdx.x >> 6, lane = threadIdx.x & 63;
  const float* er = enc2 + ((size_t)t * 16 + b) * VV;
  const float e0 = er[lane], e1 = er[lane + 64];
  for (int u = wave; u < UP1; u += 4) {
    const float* dr = dec2 + ((size_t)u * 16 + b) * VV;
    float s0 = e0 + dr[lane], s1 = e1 + dr[lane + 64];
    float mx = fmaxf(s0, s1);
#pragma unroll
    for (int off = 32; off >= 1; off >>= 1) mx = fmaxf(mx, __shfl_xor(mx, off));
    float p = __expf(s0 - mx) + __expf(s1 - mx);
#pragma unroll
    for (int off = 32; off >= 1; off >>= 1) p += __shfl_xor(p, off);
    float lsev = mx + __logf(p);
    if (u < UU) {
      int y = ys[b * UU + u];                // in [1,127]
      float sy = (y < 64) ? __shfl(s0, y) : __shfl(s1, y - 64);
      if (lane == 0) ly[((size_t)b * TT + t) * UU + u] = sy - lsev;
    }
    if (lane == 0) lb[((size_t)b * TT + t) * UP1 + u] = s0 - lsev;  // lane0: v=0
  }
}

// ---------------- anti-diagonal forward DP, one block per sample ----------------
__global__ __launch_bounds__(128) void dp_kernel(
    const float* __restrict__ lb, const float* __restrict__ ly,
    const int* __restrict__ xlen, const int* __restrict__ ylen,
    float* __restrict__ out)
{
  const int b = blockIdx.x;
  const int u = threadIdx.x;
  __shared__ float buf[2][UP1];
  const int tl = xlen[b], ul = ylen[b];
  if (u == 0) buf[0][0] = 0.f;
  __syncthreads();
  const float NEG = -1e30f;
  float nlb = 0.f, nly = 0.f;
  {
    int tn = 1 - u;
    if (u <= UU && tn >= 1 && tn < TT) nlb = lb[((size_t)b * TT + tn - 1) * UP1 + u];
    if (u >= 1 && u <= UU && tn >= 0 && tn < TT) nly = ly[((size_t)b * TT + tn) * UU + (u - 1)];
  }
  for (int d = 1; d <= TT - 1 + UU; d++) {   // up to 619
    float lbv = nlb, lyv = nly;
    {
      int tn = (d + 1) - u;
      nlb = 0.f; nly = 0.f;
      if (u <= UU && tn >= 1 && tn < TT) nlb = lb[((size_t)b * TT + tn - 1) * UP1 + u];
      if (u >= 1 && u <= UU && tn >= 0 && tn < TT) nly = ly[((size_t)b * TT + tn) * UU + (u - 1)];
    }
    const int t = d - u;
    float* cur = buf[d & 1];
    const float* prev = buf[(d & 1) ^ 1];
    if (u <= UU && t >= 0 && t < TT) {
      float a1 = (t >= 1) ? prev[u] + lbv : NEG;
      float a2 = (u >= 1) ? prev[u - 1] + lyv : NEG;
      float m = fmaxf(a1, a2);
      float val = (m <= -1e29f) ? NEG : m + __logf(1.f + __expf(-fabsf(a1 - a2)));
      cur[u] = val;
      if (t == tl - 1 && u == ul) {
        float lbt = lb[((size_t)b * TT + t) * UP1 + u];
        atomicAdd(out, -0.125f * (val + lbt));
      }
    }
    __syncthreads();
  }
}

// ---------------- launch ----------------
extern "C" void kernel_launch(void* const* d_in, const int* in_sizes, int n_in,
                              void* d_out, int out_size, void* d_ws, size_t ws_size,
                              hipStream_t stream) {
  (void)in_sizes; (void)n_in; (void)out_size;
  const float* xs    = (const float*)d_in[0];
  const int*   ys    = (const int*)d_in[1];
  const int*   xlen  = (const int*)d_in[2];
  const int*   ylen  = (const int*)d_in[3];
  const float* eWih0 = (const float*)d_in[4];
  const float* eWhh0 = (const float*)d_in[5];
  const float* ebih0 = (const float*)d_in[6];
  const float* ebhh0 = (const float*)d_in[7];
  const float* eWih1 = (const float*)d_in[8];
  const float* eWhh1 = (const float*)d_in[9];
  const float* ebih1 = (const float*)d_in[10];
  const float* ebhh1 = (const float*)d_in[11];
  const float* eWo   = (const float*)d_in[12];
  const float* ebo   = (const float*)d_in[13];
  const float* dWih  = (const float*)d_in[15];
  const float* dWhh  = (const float*)d_in[16];
  const float* dbih  = (const float*)d_in[17];
  const float* dbhh  = (const float*)d_in[18];
  const float* dWo   = (const float*)d_in[19];
  const float* dbo   = (const float*)d_in[20];

  char* ws = (char*)d_ws;
  const size_t OFF_XP0   = 1024;
  const size_t OFF_XPD   = OFF_XP0   + 20480000;  // 8*500*1280 f32
  const size_t OFF_H0    = OFF_XPD   + 4956160;   // 501 * 2560 u32 (tagged, [u][b])
  const size_t OFF_H1    = OFF_H0    + 5130240;
  const size_t OFF_HD    = OFF_H1    + 5130240;   // 122 * 2560 u32
  const size_t OFF_WB    = OFF_HD    + 1249280;
  const size_t OFF_WIH0B = OFF_WB    + 3276800;   // 4*1280*320 bf16
  const size_t OFF_XSB   = OFF_WIH0B + 245760;    // 1280*96 bf16
  const size_t OFF_WOB   = OFF_XSB   + 768000;    // 4000*96 bf16
  const size_t OFF_DWOB  = OFF_WOB   + 81920;
  const size_t OFF_B1P   = OFF_DWOB  + 81920;
  const size_t OFF_B0S   = OFF_B1P   + 5120;
  const size_t OFF_ENC2  = OFF_B0S   + 5120;
  const size_t OFF_DEC2  = OFF_ENC2  + 4096000;   // 500*16*128 f32
  const size_t OFF_LB    = OFF_DEC2  + 991232;    // 121*16*128 f32
  const size_t OFF_LY    = OFF_LB    + 1936000;   // 8*500*121 f32
  const size_t OFF_CN0   = OFF_LY    + 1920000;   // 512 u32 step counters per stage
  const size_t OFF_CN1   = OFF_CN0   + 2048;
  const size_t OFF_CND   = OFF_CN1   + 2048;
  const size_t OFF_XP1   = OFF_CND   + 2048;      // 500*8*1280 tagged f32
  const size_t TOTAL     = OFF_XP1   + 20480000;
  if (ws_size < TOTAL) return;

  float*    xp0   = (float*)(ws + OFF_XP0);
  float*    xpd   = (float*)(ws + OFF_XPD);
  unsigned* h0    = (unsigned*)(ws + OFF_H0);
  unsigned* h1    = (unsigned*)(ws + OFF_H1);
  unsigned* hd    = (unsigned*)(ws + OFF_HD);
  ushort*   wb    = (ushort*)(ws + OFF_WB);
  ushort*   wih0b = (ushort*)(ws + OFF_WIH0B);
  ushort*   xsb   = (ushort*)(ws + OFF_XSB);
  ushort*   wob   = (ushort*)(ws + OFF_WOB);
  ushort*   dwob  = (ushort*)(ws + OFF_DWOB);
  float*    b1p   = (float*)(ws + OFF_B1P);
  float*    b0s   = (float*)(ws + OFF_B0S);
  float*    enc2  = (float*)(ws + OFF_ENC2);
  float*    dec2  = (float*)(ws + OFF_DEC2);
  float*    lb    = (float*)(ws + OFF_LB);
  float*    ly    = (float*)(ws + OFF_LY);
  unsigned* cn0   = (unsigned*)(ws + OFF_CN0);
  unsigned* cn1   = (unsigned*)(ws + OFF_CN1);
  unsigned* cnd   = (unsigned*)(ws + OFF_CND);
  unsigned* xp1   = (unsigned*)(ws + OFF_XP1);
  float*    out   = (float*)d_out;

  hipLaunchKernelGGL(prep_zero, dim3(1), dim3(512), 0, stream, cn0, cn1, cnd, out);
  hipLaunchKernelGGL(prep_w, dim3(8710), dim3(256), 0, stream,
                     eWhh0, eWih1, eWhh1, dWhh, eWih0, xs, eWo, dWo,
                     ebih1, ebhh1, ebih0, ebhh0,
                     wb, wih0b, xsb, wob, dwob, b1p, b0s);
  hipLaunchKernelGGL(xproj0_mfma, dim3(250), dim3(256), 0, stream, xsb, wih0b, b0s, xp0);
  hipLaunchKernelGGL(xprojd_g, dim3(968), dim3(256), 0, stream, ys, dWih, dbih, dbhh, xpd);
  hipLaunchKernelGGL(lstm_fused, dim3(20), dim3(512), 0, stream,
                     wb, b1p, xp0, xpd, h0, h1, hd, xp1, cn0, cn1, cnd);
  hipLaunchKernelGGL(proj_mfma, dim3(500), dim3(256), 0, stream, h1, wob, ebo, enc2);
  hipLaunchKernelGGL(proj_mfma, dim3(121), dim3(256), 0, stream, hd, dwob, dbo, dec2);
  hipLaunchKernelGGL(lse_kernel, dim3(4000), dim3(256), 0, stream, enc2, dec2, ys, lb, ly);
  hipLaunchKernelGGL(dp_kernel, dim3(8), dim3(128), 0, stream, lb, ly, xlen, ylen, out);
}

// Round 8
// 1938.478 us; speedup vs baseline: 1.0982x; 1.0982x over previous
//
#include <hip/hip_runtime.h>

typedef __attribute__((ext_vector_type(8))) short s8v;   // 8 x bf16 (4 VGPRs)
typedef __attribute__((ext_vector_type(4))) float f4v;   // MFMA accumulator

#define BB 8
#define TT 500
#define UU 120
#define UP1 121
#define VV 128
#define HH 320
#define G4 1280

// ---------------- helpers ----------------
__device__ __forceinline__ unsigned short f2bf(float x) {
  unsigned u = __builtin_bit_cast(unsigned, x);
  unsigned r = (u + 0x7FFFu + ((u >> 16) & 1u)) >> 16;  // RNE
  return (unsigned short)r;
}
__device__ __forceinline__ float sigf(float x)   { return 1.f / (1.f + __expf(-x)); }
__device__ __forceinline__ float tanh_f(float x) { return 2.f / (1.f + __expf(-2.f * x)) - 1.f; }

// agent-scope (L3-coherent) relaxed atomics — proven transport
__device__ __forceinline__ unsigned ald32(const unsigned* p) {
  return __hip_atomic_load((unsigned*)p, __ATOMIC_RELAXED, __HIP_MEMORY_SCOPE_AGENT);
}
__device__ __forceinline__ void ast32(unsigned* p, unsigned v) {
  __hip_atomic_store(p, v, __ATOMIC_RELAXED, __HIP_MEMORY_SCOPE_AGENT);
}

// ---------------- prep: out init ----------------
__global__ void prep_zero(float* out) {
  if (threadIdx.x == 0 && blockIdx.x == 0) out[0] = 0.f;
}

// ---------------- prep: bf16 conversions + bias folds ----------------
__global__ void prep_w(
    const float* __restrict__ whh0, const float* __restrict__ wih1,
    const float* __restrict__ whh1, const float* __restrict__ whhd,
    const float* __restrict__ wih0, const float* __restrict__ xs,
    const float* __restrict__ ewo,  const float* __restrict__ dwo,
    const float* __restrict__ bih1, const float* __restrict__ bhh1,
    const float* __restrict__ bih0, const float* __restrict__ bhh0,
    ushort* __restrict__ wb, ushort* __restrict__ wih0b, ushort* __restrict__ xsb,
    ushort* __restrict__ wob, ushort* __restrict__ dwob,
    float* __restrict__ bias1p, float* __restrict__ b0s)
{
  int i = blockIdx.x * blockDim.x + threadIdx.x;
  if (i < 1638400) {                       // 4 recurrent-ish mats [1280][320]
    int m = i / 409600, e = i - m * 409600;
    const float* src = (m == 0) ? whh0 : (m == 1) ? wih1 : (m == 2) ? whh1 : whhd;
    wb[i] = f2bf(src[e]);
  } else if (i < 1761280) {                // Wih0 [1280][80] -> [1280][96] zero-padded
    int e = i - 1638400;
    int row = e / 96, k = e - row * 96;
    wih0b[e] = (k < 80) ? f2bf(wih0[row * 80 + k]) : (ushort)0;
  } else if (i < 2145280) {                // xs [4000][80] -> [4000][96] zero-padded
    int e = i - 1761280;
    int row = e / 96, k = e - row * 96;
    xsb[e] = (k < 80) ? f2bf(xs[row * 80 + k]) : (ushort)0;
  } else if (i < 2186240) {                // enc_Wo [128][320]
    int e = i - 2145280;
    wob[e] = f2bf(ewo[e]);
  } else if (i < 2227200) {                // dec_Wo [128][320]
    int e = i - 2186240;
    dwob[e] = f2bf(dwo[e]);
  } else if (i < 2228480) {                // bias1 permuted [unit][gate]
    int e = i - 2227200;
    int uq = e >> 2, gq = e & 3;
    bias1p[e] = bih1[gq * HH + uq] + bhh1[gq * HH + uq];
  } else if (i < 2229760) {                // bih0+bhh0 summed (gate-row order)
    int e = i - 2228480;
    b0s[e] = bih0[e] + bhh0[e];
  }
}

// ---------------- xproj for layer0: [4000,96]bf16 @ [96,1280] -> xp0[b][t][u][g] f32 ----------------
__global__ __launch_bounds__(256) void xproj0_mfma(
    const ushort* __restrict__ xsb, const ushort* __restrict__ wih0b,
    const float* __restrict__ b0s, float* __restrict__ xp0)
{
  const int mt = blockIdx.x;                 // 250 tiles of 16 (b,t)-rows
  const int wave = threadIdx.x >> 6, lane = threadIdx.x & 63;
  const int q = lane >> 4, n16 = lane & 15;
  s8v a[3];
#pragma unroll
  for (int kt = 0; kt < 3; kt++)
    a[kt] = *(const s8v*)(xsb + (mt * 16 + n16) * 96 + kt * 32 + q * 8);
  for (int nt = wave; nt < 80; nt += 4) {
    s8v bf[3];
#pragma unroll
    for (int kt = 0; kt < 3; kt++)
      bf[kt] = *(const s8v*)(wih0b + (nt * 16 + n16) * 96 + kt * 32 + q * 8);
    f4v acc = {0.f, 0.f, 0.f, 0.f};
#pragma unroll
    for (int kt = 0; kt < 3; kt++)
      acc = __builtin_amdgcn_mfma_f32_16x16x32_bf16(a[kt], bf[kt], acc, 0, 0, 0);
    const int gr = nt * 16 + n16;            // D col = gate row
    const int gg = gr / HH;
    const int uu = gr - gg * HH;
    const float bias = b0s[gr];
#pragma unroll
    for (int r = 0; r < 4; r++) {
      int bt = mt * 16 + 4 * q + r;          // D row = (b,t) row
      xp0[(size_t)bt * G4 + uu * 4 + gg] = acc[r] + bias;
    }
  }
}

// ---------------- decoder input projection: one-hot gather ----------------
__global__ __launch_bounds__(256) void xprojd_g(
    const int* __restrict__ ys, const float* __restrict__ dWih,
    const float* __restrict__ dbih, const float* __restrict__ dbhh,
    float* __restrict__ xpd)
{
  const int blk = blockIdx.x;                // 968 = 8 * 121
  const int b = blk / UP1, u = blk - b * UP1;
  int colv = -1;
  if (u > 0) colv = ys[b * UU + (u - 1)] - 1;   // embed row id>=1 -> one-hot at id-1
  for (int i = threadIdx.x; i < G4; i += 256) {
    int uu = i >> 2, gg = i & 3;
    int row = gg * HH + uu;
    float v = dbih[row] + dbhh[row];
    if (colv >= 0) v += dWih[row * 127 + colv];
    xpd[((size_t)b * UP1 + u) * G4 + i] = v;
  }
}

// ======================================================================
// Fused recurrences v6: R7 structure, transport = DIRECT bulk tag-poll.
// 20 WGs x 512 thr: wg0-4 stage0, wg5-9 stage1, wg10-14 dec, wg15-19 relay.
// Change from R7 (counters removed entirely): producers store LSB-tagged
// values and continue — NO vmcnt(0) drain, NO atomicAdd, NO gate. Consumers
// detect readiness on the data itself: the 5 bulk loads for step t+1 are
// issued immediately after the step-t store (flight overlaps the producers'
// store-landing window), and the resolve loop re-issues only on tag miss.
// This cuts ~2 serial L3/HBM round trips per step vs the R3/R6 counter gate
// (drain + atomic-visibility + gate-detect collapse into data-landing).
// Tag scheme is R0's proven one: payload LSB=1, poison 0xAA.. is even.
// Everything else unchanged: relay offload of Wih1@h0 (one-way, tagged f32
// xp1), deferred C-init resolve after MFMAs, tile0-in-regs + tile1-in-LDS
// weights, packed h [t][u][b] (2-4 lines per producer wave).
// ======================================================================
__global__ __launch_bounds__(512, 1) void lstm_fused(
    const ushort* __restrict__ wb, const float* __restrict__ b1p,
    const float* __restrict__ xp0, const float* __restrict__ xpd,
    unsigned* __restrict__ h0u, unsigned* __restrict__ h1u, unsigned* __restrict__ hdu,
    unsigned* __restrict__ xp1u)
{
  __shared__ ushort hbS[2][16][328];         // 21KB  h double-buffer [b][u]
  __shared__ s8v wlds[8][10][64];            // 80KB  tile1 weight frags

  const int wg = blockIdx.x;
  const int tid = threadIdx.x;
  const int wave = tid >> 6, lane = tid & 63;
  const int q = lane >> 4, n16 = lane & 15;
  const int uloc = n16 >> 2, g = n16 & 3;
  const int bcol = n16 & 7;
  const bool act = (n16 < BB);

  // zero both LDS h buffers (t=0 state = zeros; rows 8..15 stay zero forever)
  for (int i = tid; i < 2 * 16 * 328; i += 512) ((ushort*)hbS)[i] = 0;

  if (wg >= 15) {
    // ================= relay: xp1[s] = Wih1 @ h0[s+1] + b1 =================
    const int rw = wg - 15;
    const int w = rw * 8 + wave;
    const int ubase = w * 8;
    const ushort* Win = wb + 409600;         // Wih1
    s8v afr0[10];
    {
      const int arow0 = g * HH + ubase + uloc;
      const int arow1 = g * HH + ubase + 4 + uloc;
#pragma unroll
      for (int kt = 0; kt < 10; kt++) {
        afr0[kt] = *(const s8v*)(Win + arow0 * HH + kt * 32 + q * 8);
        wlds[wave][kt][lane] = *(const s8v*)(Win + arow1 * HH + kt * 32 + q * 8);
      }
    }
    f4v bias4[2];
#pragma unroll
    for (int tile = 0; tile < 2; tile++)
      bias4[tile] = *(const f4v*)(b1p + (ubase + tile * 4 + q) * 4);

    // pre-issue h0[1] bulk loads
    unsigned v[5];
    {
      const unsigned* p = h0u + 2560 + wave * 320 + lane;
#pragma unroll
      for (int j = 0; j < 5; j++) v[j] = ald32(p + j * 64);
    }
    __syncthreads();                         // weight-LDS + hbS zeros visible

    for (int s = 0; s < TT; s++) {
      const int pb = s & 1;
      // resolve pre-issued h0[s+1] reads (retry on tag miss)
      {
        const unsigned* p = h0u + (size_t)(s + 1) * 2560 + wave * 320 + lane;
        int tries = 0;
        for (;;) {
          unsigned a = v[0] & v[1] & v[2] & v[3] & v[4];
          if (__all((int)(a & 1u)) || ++tries > (1 << 17)) break;
          if (tries > 64) __builtin_amdgcn_s_sleep(1);
#pragma unroll
          for (int j = 0; j < 5; j++) v[j] = ald32(p + j * 64);
        }
#pragma unroll
        for (int j = 0; j < 5; j++) {
          int f = wave * 320 + j * 64 + lane;          // u = f>>3, b = f&7
          hbS[pb][f & 7][f >> 3] = (ushort)(v[j] >> 16);
        }
      }
      __syncthreads();
      // issue next step's bulk loads now; flight hides under MFMA + stores
      if (s + 1 < TT) {
        const unsigned* p = h0u + (size_t)(s + 2) * 2560 + wave * 320 + lane;
#pragma unroll
        for (int j = 0; j < 5; j++) v[j] = ald32(p + j * 64);
      }

      f4v acc[2];
      acc[0] = bias4[0]; acc[1] = bias4[1];
#pragma unroll
      for (int kt = 0; kt < 10; kt++) {
        s8v b = *(const s8v*)&hbS[pb][n16][kt * 32 + q * 8];
        acc[0] = __builtin_amdgcn_mfma_f32_16x16x32_bf16(afr0[kt], b, acc[0], 0, 0, 0);
        s8v a1 = wlds[wave][kt][lane];
        acc[1] = __builtin_amdgcn_mfma_f32_16x16x32_bf16(a1, b, acc[1], 0, 0, 0);
      }
      if (act) {
#pragma unroll
        for (int tile = 0; tile < 2; tile++) {
          unsigned* dp = xp1u + (size_t)((unsigned)s * 8u + (unsigned)n16) * G4
                       + (unsigned)((ubase + tile * 4 + q) * 4);
#pragma unroll
          for (int r = 0; r < 4; r++)
            ast32(dp + r, __float_as_uint(acc[tile][r]) | 1u);   // LSB tag on f32
        }
      }
    }
    return;
  }

  // ================= recurrent stages =================
  const int stage = wg / 5;
  const int gw = wg - stage * 5;
  const int w = gw * 8 + wave;              // wave-in-stage [0,40)
  const int ubase = w * 8;                  // this wave owns units [ubase, ubase+8)

  const ushort* A = wb + (stage == 0 ? 0 : (stage == 1 ? 819200 : 1228800));
  // tile0 -> regs (40 VGPR), tile1 -> LDS
  s8v afr0[10];
  {
    const int arow0 = g * HH + ubase + uloc;
    const int arow1 = g * HH + ubase + 4 + uloc;
#pragma unroll
    for (int kt = 0; kt < 10; kt++) {
      afr0[kt] = *(const s8v*)(A + arow0 * HH + kt * 32 + q * 8);
      wlds[wave][kt][lane] = *(const s8v*)(A + arow1 * HH + kt * 32 + q * 8);
    }
  }

  const int steps = (stage == 2) ? UP1 : TT;
  unsigned* hio = (stage == 0) ? h0u : ((stage == 1) ? h1u : hdu);

  const float* xq = 0;
  if (stage == 0)      xq = xp0 + (size_t)bcol * TT * G4;
  else if (stage == 2) xq = xpd + (size_t)bcol * UP1 * G4;

  float c0 = 0.f, c1 = 0.f;
  unsigned hv5[5];                           // in-flight bulk h reads
  __syncthreads();                           // LDS zeros + weight-LDS visible

  for (int t = 0; t < steps; t++) {
    const int pb = t & 1;

    // ---- pre-issue C-init inputs; consumed after the MFMA block ----
    f4v xq4[2];
    unsigned xv[2][4];
    if (stage != 1) {
#pragma unroll
      for (int tile = 0; tile < 2; tile++)
        xq4[tile] = *(const f4v*)(xq + (size_t)t * G4 + (ubase + tile * 4 + q) * 4);
    } else {
#pragma unroll
      for (int tile = 0; tile < 2; tile++) {
        const unsigned* xpp = xp1u + (size_t)((unsigned)t * 8u + (unsigned)bcol) * G4
                            + (unsigned)((ubase + tile * 4 + q) * 4);
#pragma unroll
        for (int r = 0; r < 4; r++) xv[tile][r] = ald32(xpp + r);
      }
    }

    // ---- resolve pre-issued bulk h[t] reads, transpose-relay into LDS ----
    if (t > 0) {
      const unsigned* src = hio + (size_t)t * 2560 + wave * 320 + lane;
      int tries = 0;
      for (;;) {
        unsigned a = hv5[0] & hv5[1] & hv5[2] & hv5[3] & hv5[4];
        if (__all((int)(a & 1u)) || ++tries > (1 << 17)) break;
        if (tries > 64) __builtin_amdgcn_s_sleep(1);
#pragma unroll
        for (int j = 0; j < 5; j++) hv5[j] = ald32(src + j * 64);
      }
#pragma unroll
      for (int j = 0; j < 5; j++) {
        int f = wave * 320 + j * 64 + lane;            // u = f>>3, b = f&7
        hbS[pb][f & 7][f >> 3] = (ushort)(hv5[j] >> 16);
      }
    }
    __syncthreads();

    // ---- MFMAs: B-frags from LDS h(t); tile1 A-frags from LDS ----
    f4v acc[2];
    acc[0] = (f4v){0.f, 0.f, 0.f, 0.f};
    acc[1] = (f4v){0.f, 0.f, 0.f, 0.f};
#pragma unroll
    for (int kt = 0; kt < 10; kt++) {
      s8v b = *(const s8v*)&hbS[pb][n16][kt * 32 + q * 8];
      acc[0] = __builtin_amdgcn_mfma_f32_16x16x32_bf16(afr0[kt], b, acc[0], 0, 0, 0);
      s8v a1 = wlds[wave][kt][lane];
      acc[1] = __builtin_amdgcn_mfma_f32_16x16x32_bf16(a1, b, acc[1], 0, 0, 0);
    }

    // ---- resolve C-init (deferred add; stage1 tag-spins on relay output) ----
    if (stage != 1) {
#pragma unroll
      for (int tile = 0; tile < 2; tile++) {
        acc[tile][0] += xq4[tile][0]; acc[tile][1] += xq4[tile][1];
        acc[tile][2] += xq4[tile][2]; acc[tile][3] += xq4[tile][3];
      }
    } else {
      int tries = 0;
      for (;;) {
        unsigned m = xv[0][0] & xv[0][1] & xv[0][2] & xv[0][3]
                   & xv[1][0] & xv[1][1] & xv[1][2] & xv[1][3];
        bool ok = (!act) || ((m & 1u) != 0u);
        if (__all((int)ok) || ++tries > (1 << 17)) break;
        if (tries > 64) __builtin_amdgcn_s_sleep(1);
#pragma unroll
        for (int tile = 0; tile < 2; tile++) {
          const unsigned* xpp = xp1u + (size_t)((unsigned)t * 8u + (unsigned)bcol) * G4
                              + (unsigned)((ubase + tile * 4 + q) * 4);
#pragma unroll
          for (int r = 0; r < 4; r++) xv[tile][r] = ald32(xpp + r);
        }
      }
#pragma unroll
      for (int tile = 0; tile < 2; tile++)
#pragma unroll
        for (int r = 0; r < 4; r++)
          acc[tile][r] += __uint_as_float(xv[tile][r] & ~1u);
    }

    // ---- lane-local LSTM cell ----
    float hv0, hv1;
    {
      float ig = sigf(acc[0][0]), fg = sigf(acc[0][1]);
      float gv = tanh_f(acc[0][2]), og = sigf(acc[0][3]);
      c0 = fg * c0 + ig * gv; hv0 = og * tanh_f(c0);
    }
    {
      float ig = sigf(acc[1][0]), fg = sigf(acc[1][1]);
      float gv = tanh_f(acc[1][2]), og = sigf(acc[1][3]);
      c1 = fg * c1 + ig * gv; hv1 = og * tanh_f(c1);
    }
    if (act) {
      // packed [u][b] store: wave's 16 stores span 2-4 cache lines; no drain
      unsigned* dst = hio + (size_t)(t + 1) * 2560;
      ast32(dst + (ubase + q) * 8 + n16,     (((unsigned)f2bf(hv0)) << 16) | 1u);
      ast32(dst + (ubase + 4 + q) * 8 + n16, (((unsigned)f2bf(hv1)) << 16) | 1u);
    }

    // ---- issue next step's bulk h reads: flight overlaps store landing ----
    if (t + 1 < steps) {
      const unsigned* src = hio + (size_t)(t + 1) * 2560 + wave * 320 + lane;
#pragma unroll
      for (int j = 0; j < 5; j++) hv5[j] = ald32(src + j * 64);
    }
  }
}

// ---------------- output projections: h(tagged u32, [u][b]) @ Wo^T -> out2[t][16][128] ----------------
__global__ __launch_bounds__(256) void proj_mfma(
    const unsigned* __restrict__ hseq, const ushort* __restrict__ wo,
    const float* __restrict__ bo, float* __restrict__ out2)
{
  __shared__ ushort hl[16][328];
  const int t = blockIdx.x;
  const int tid = threadIdx.x;
  const int wave = tid >> 6, lane = tid & 63;
  const int q = lane >> 4, n16 = lane & 15;
  // zero rows 8..15 (unused MFMA B-columns)
  for (int i = tid; i < 8 * 328; i += 256) hl[8 + i / 328][i % 328] = 0;
  // coalesced load + transpose: flat idx f -> u=f>>3, b=f&7
  for (int f = tid; f < 2560; f += 256) {
    unsigned v = hseq[(size_t)(t + 1) * 2560 + f];
    hl[f & 7][f >> 3] = (ushort)(v >> 16);
  }
  __syncthreads();
  s8v a[10];
#pragma unroll
  for (int kt = 0; kt < 10; kt++)
    a[kt] = *(const s8v*)&hl[n16][kt * 32 + q * 8];
  for (int j = 0; j < 2; j++) {
    int nt = wave * 2 + j;
    s8v bf[10];
#pragma unroll
    for (int kt = 0; kt < 10; kt++)
      bf[kt] = *(const s8v*)(wo + (nt * 16 + n16) * HH + kt * 32 + q * 8);
    f4v acc = {0.f, 0.f, 0.f, 0.f};
#pragma unroll
    for (int kt = 0; kt < 10; kt++)
      acc = __builtin_amdgcn_mfma_f32_16x16x32_bf16(a[kt], bf[kt], acc, 0, 0, 0);
    int v = nt * 16 + n16;
    float bias = bo[v];
    if (q < 2) {
#pragma unroll
      for (int r = 0; r < 4; r++) {
        int b = 4 * q + r;                   // D row = batch
        out2[((size_t)t * 16 + b) * VV + v] = acc[r] + bias;
      }
    }
  }
}

// ---------------- per-cell logsumexp over V: produce lb[b][t][u], ly[b][t][u] ----------------
__global__ __launch_bounds__(256) void lse_kernel(
    const float* __restrict__ enc2, const float* __restrict__ dec2,
    const int* __restrict__ ys, float* __restrict__ lb, float* __restrict__ ly)
{
  const int blk = blockIdx.x;                // 4000 = 8*500
  const int b = blk / TT, t = blk - b * TT;
  const int wave = threadIdx.x >> 6, lane = threadIdx.x & 63;
  const float* er = enc2 + ((size_t)t * 16 + b) * VV;
  const float e0 = er[lane], e1 = er[lane + 64];
  for (int u = wave; u < UP1; u += 4) {
    const float* dr = dec2 + ((size_t)u * 16 + b) * VV;
    float s0 = e0 + dr[lane], s1 = e1 + dr[lane + 64];
    float mx = fmaxf(s0, s1);
#pragma unroll
    for (int off = 32; off >= 1; off >>= 1) mx = fmaxf(mx, __shfl_xor(mx, off));
    float p = __expf(s0 - mx) + __expf(s1 - mx);
#pragma unroll
    for (int off = 32; off >= 1; off >>= 1) p += __shfl_xor(p, off);
    float lsev = mx + __logf(p);
    if (u < UU) {
      int y = ys[b * UU + u];                // in [1,127]
      float sy = (y < 64) ? __shfl(s0, y) : __shfl(s1, y - 64);
      if (lane == 0) ly[((size_t)b * TT + t) * UU + u] = sy - lsev;
    }
    if (lane == 0) lb[((size_t)b * TT + t) * UP1 + u] = s0 - lsev;  // lane0: v=0
  }
}

// ---------------- anti-diagonal forward DP, one block per sample ----------------
__global__ __launch_bounds__(128) void dp_kernel(
    const float* __restrict__ lb, const float* __restrict__ ly,
    const int* __restrict__ xlen, const int* __restrict__ ylen,
    float* __restrict__ out)
{
  const int b = blockIdx.x;
  const int u = threadIdx.x;
  __shared__ float buf[2][UP1];
  const int tl = xlen[b], ul = ylen[b];
  if (u == 0) buf[0][0] = 0.f;
  __syncthreads();
  const float NEG = -1e30f;
  float nlb = 0.f, nly = 0.f;
  {
    int tn = 1 - u;
    if (u <= UU && tn >= 1 && tn < TT) nlb = lb[((size_t)b * TT + tn - 1) * UP1 + u];
    if (u >= 1 && u <= UU && tn >= 0 && tn < TT) nly = ly[((size_t)b * TT + tn) * UU + (u - 1)];
  }
  for (int d = 1; d <= TT - 1 + UU; d++) {   // up to 619
    float lbv = nlb, lyv = nly;
    {
      int tn = (d + 1) - u;
      nlb = 0.f; nly = 0.f;
      if (u <= UU && tn >= 1 && tn < TT) nlb = lb[((size_t)b * TT + tn - 1) * UP1 + u];
      if (u >= 1 && u <= UU && tn >= 0 && tn < TT) nly = ly[((size_t)b * TT + tn) * UU + (u - 1)];
    }
    const int t = d - u;
    float* cur = buf[d & 1];
    const float* prev = buf[(d & 1) ^ 1];
    if (u <= UU && t >= 0 && t < TT) {
      float a1 = (t >= 1) ? prev[u] + lbv : NEG;
      float a2 = (u >= 1) ? prev[u - 1] + lyv : NEG;
      float m = fmaxf(a1, a2);
      float val = (m <= -1e29f) ? NEG : m + __logf(1.f + __expf(-fabsf(a1 - a2)));
      cur[u] = val;
      if (t == tl - 1 && u == ul) {
        float lbt = lb[((size_t)b * TT + t) * UP1 + u];
        atomicAdd(out, -0.125f * (val + lbt));
      }
    }
    __syncthreads();
  }
}

// ---------------- launch ----------------
extern "C" void kernel_launch(void* const* d_in, const int* in_sizes, int n_in,
                              void* d_out, int out_size, void* d_ws, size_t ws_size,
                              hipStream_t stream) {
  (void)in_sizes; (void)n_in; (void)out_size;
  const float* xs    = (const float*)d_in[0];
  const int*   ys    = (const int*)d_in[1];
  const int*   xlen  = (const int*)d_in[2];
  const int*   ylen  = (const int*)d_in[3];
  const float* eWih0 = (const float*)d_in[4];
  const float* eWhh0 = (const float*)d_in[5];
  const float* ebih0 = (const float*)d_in[6];
  const float* ebhh0 = (const float*)d_in[7];
  const float* eWih1 = (const float*)d_in[8];
  const float* eWhh1 = (const float*)d_in[9];
  const float* ebih1 = (const float*)d_in[10];
  const float* ebhh1 = (const float*)d_in[11];
  const float* eWo   = (const float*)d_in[12];
  const float* ebo   = (const float*)d_in[13];
  const float* dWih  = (const float*)d_in[15];
  const float* dWhh  = (const float*)d_in[16];
  const float* dbih  = (const float*)d_in[17];
  const float* dbhh  = (const float*)d_in[18];
  const float* dWo   = (const float*)d_in[19];
  const float* dbo   = (const float*)d_in[20];

  char* ws = (char*)d_ws;
  const size_t OFF_XP0   = 1024;
  const size_t OFF_XPD   = OFF_XP0   + 20480000;  // 8*500*1280 f32
  const size_t OFF_H0    = OFF_XPD   + 4956160;   // 501 * 2560 u32 (tagged, [u][b])
  const size_t OFF_H1    = OFF_H0    + 5130240;
  const size_t OFF_HD    = OFF_H1    + 5130240;   // 122 * 2560 u32
  const size_t OFF_WB    = OFF_HD    + 1249280;
  const size_t OFF_WIH0B = OFF_WB    + 3276800;   // 4*1280*320 bf16
  const size_t OFF_XSB   = OFF_WIH0B + 245760;    // 1280*96 bf16
  const size_t OFF_WOB   = OFF_XSB   + 768000;    // 4000*96 bf16
  const size_t OFF_DWOB  = OFF_WOB   + 81920;
  const size_t OFF_B1P   = OFF_DWOB  + 81920;
  const size_t OFF_B0S   = OFF_B1P   + 5120;
  const size_t OFF_ENC2  = OFF_B0S   + 5120;
  const size_t OFF_DEC2  = OFF_ENC2  + 4096000;   // 500*16*128 f32
  const size_t OFF_LB    = OFF_DEC2  + 991232;    // 121*16*128 f32
  const size_t OFF_LY    = OFF_LB    + 1936000;   // 8*500*121 f32
  const size_t OFF_XP1   = OFF_LY    + 1920000;   // 500*8*1280 tagged f32
  const size_t TOTAL     = OFF_XP1   + 20480000;
  if (ws_size < TOTAL) return;

  float*    xp0   = (float*)(ws + OFF_XP0);
  float*    xpd   = (float*)(ws + OFF_XPD);
  unsigned* h0    = (unsigned*)(ws + OFF_H0);
  unsigned* h1    = (unsigned*)(ws + OFF_H1);
  unsigned* hd    = (unsigned*)(ws + OFF_HD);
  ushort*   wb    = (ushort*)(ws + OFF_WB);
  ushort*   wih0b = (ushort*)(ws + OFF_WIH0B);
  ushort*   xsb   = (ushort*)(ws + OFF_XSB);
  ushort*   wob   = (ushort*)(ws + OFF_WOB);
  ushort*   dwob  = (ushort*)(ws + OFF_DWOB);
  float*    b1p   = (float*)(ws + OFF_B1P);
  float*    b0s   = (float*)(ws + OFF_B0S);
  float*    enc2  = (float*)(ws + OFF_ENC2);
  float*    dec2  = (float*)(ws + OFF_DEC2);
  float*    lb    = (float*)(ws + OFF_LB);
  float*    ly    = (float*)(ws + OFF_LY);
  unsigned* xp1   = (unsigned*)(ws + OFF_XP1);
  float*    out   = (float*)d_out;

  hipLaunchKernelGGL(prep_zero, dim3(1), dim3(64), 0, stream, out);
  hipLaunchKernelGGL(prep_w, dim3(8710), dim3(256), 0, stream,
                     eWhh0, eWih1, eWhh1, dWhh, eWih0, xs, eWo, dWo,
                     ebih1, ebhh1, ebih0, ebhh0,
                     wb, wih0b, xsb, wob, dwob, b1p, b0s);
  hipLaunchKernelGGL(xproj0_mfma, dim3(250), dim3(256), 0, stream, xsb, wih0b, b0s, xp0);
  hipLaunchKernelGGL(xprojd_g, dim3(968), dim3(256), 0, stream, ys, dWih, dbih, dbhh, xpd);
  hipLaunchKernelGGL(lstm_fused, dim3(20), dim3(512), 0, stream,
                     wb, b1p, xp0, xpd, h0, h1, hd, xp1);
  hipLaunchKernelGGL(proj_mfma, dim3(500), dim3(256), 0, stream, h1, wob, ebo, enc2);
  hipLaunchKernelGGL(proj_mfma, dim3(121), dim3(256), 0, stream, hd, dwob, dbo, dec2);
  hipLaunchKernelGGL(lse_kernel, dim3(4000), dim3(256), 0, stream, enc2, dec2, ys, lb, ly);
  hipLaunchKernelGGL(dp_kernel, dim3(8), dim3(128), 0, stream, lb, ly, xlen, ylen, out);
}